// Round 1
// baseline (450.402 us; speedup 1.0000x reference)
//
#include <hip/hip_runtime.h>

#define DEV __device__ __forceinline__

typedef __attribute__((ext_vector_type(8))) short bf16x8;
typedef __attribute__((ext_vector_type(8))) unsigned short u16x8;
typedef __attribute__((ext_vector_type(4))) float f32x4;

DEV unsigned short f2bf(float f) {
  unsigned int u = __float_as_uint(f);
  u += 0x7FFFu + ((u >> 16) & 1u);   // round-to-nearest-even
  return (unsigned short)(u >> 16);
}
DEV float bf2f(unsigned short h) { return __uint_as_float(((unsigned int)h) << 16); }

// LDS swizzle: rows are 128 bytes; XOR 16B-slot with (row&7) -> bank-balanced
// ds_read_b128 / ds_write_b128 (G4 fix for stride-128B column reads).
DEV int swz(int row, int byteoff) { return row * 128 + (byteoff ^ ((row & 7) << 4)); }

// ---------------------------------------------------------------- cvt fp32->bf16
__global__ void cvt_kernel(const float* __restrict__ src, unsigned short* __restrict__ dst,
                           float* __restrict__ dstf, int n) {
  long i = ((long)blockIdx.x * blockDim.x + threadIdx.x) * 8;
  long stride = (long)gridDim.x * blockDim.x * 8;
  for (; i < n; i += stride) {
    f32x4 a = *(const f32x4*)(src + i);
    f32x4 b = *(const f32x4*)(src + i + 4);
    u16x8 o;
    o[0] = f2bf(a[0]); o[1] = f2bf(a[1]); o[2] = f2bf(a[2]); o[3] = f2bf(a[3]);
    o[4] = f2bf(b[0]); o[5] = f2bf(b[1]); o[6] = f2bf(b[2]); o[7] = f2bf(b[3]);
    *(u16x8*)(dst + i) = o;
    if (dstf) { *(f32x4*)(dstf + i) = a; *(f32x4*)(dstf + i + 4) = b; }
  }
}

// ---------------------------------------------------------------- GEMM
// Y[m,n] = act( sum_k X[m,k]*W[n,k] + bias[n] ), X:(M,K) bf16, W:(N,K) bf16.
// 64x64 tile, BK=64, 4 waves (2x2), wave does 32x32 = 2x2 mfma_16x16x32 frags.
// Batched via blockIdx.z with element strides (xbs/wbs/bbs/ybs).
template <int ACT, int WF32, int WBF>
__global__ __launch_bounds__(256) void gemm_kernel(
    const unsigned short* __restrict__ X, const unsigned short* __restrict__ Wt,
    const float* __restrict__ bias, float* Yf, unsigned short* Ybf,
    int M, int N, int K, long xbs, long wbs, long bbs, long ybs) {
  __shared__ __align__(16) unsigned short As[64 * 64];
  __shared__ __align__(16) unsigned short Bs[64 * 64];
  const int t = threadIdx.x;
  const int bn = blockIdx.x, bm = blockIdx.y, bz = blockIdx.z;
  const unsigned short* Xp = X + (long)bz * xbs;
  const unsigned short* Wp = Wt + (long)bz * wbs;
  const float* bp = bias + (long)bz * bbs;

  const int lane = t & 63, wv = t >> 6;
  const int wr = wv >> 1, wc = wv & 1;
  f32x4 acc[2][2] = {};

  const int r = t >> 2;  // staging row 0..63
  const int q = t & 3;   // 32-byte quarter of the 128B row
  const long xrow = (long)(bm * 64 + r) * K;
  const long wrow = (long)(bn * 64 + r) * K;
  char* Asb = (char*)As;
  char* Bsb = (char*)Bs;

  for (int kt = 0; kt < K; kt += 64) {
    const unsigned short* ga = Xp + xrow + kt + q * 16;
    const unsigned short* gb = Wp + wrow + kt + q * 16;
    u16x8 a0 = *(const u16x8*)ga;
    u16x8 a1 = *(const u16x8*)(ga + 8);
    u16x8 b0 = *(const u16x8*)gb;
    u16x8 b1 = *(const u16x8*)(gb + 8);
    *(u16x8*)(Asb + swz(r, q * 32)) = a0;
    *(u16x8*)(Asb + swz(r, q * 32 + 16)) = a1;
    *(u16x8*)(Bsb + swz(r, q * 32)) = b0;
    *(u16x8*)(Bsb + swz(r, q * 32 + 16)) = b1;
    __syncthreads();
#pragma unroll
    for (int kk = 0; kk < 2; ++kk) {
      const int kb = kk * 64 + ((lane >> 4) << 4);
      bf16x8 af[2], bfr[2];
#pragma unroll
      for (int mi = 0; mi < 2; ++mi)
        af[mi] = *(const bf16x8*)(Asb + swz(wr * 32 + mi * 16 + (lane & 15), kb));
#pragma unroll
      for (int ni = 0; ni < 2; ++ni)
        bfr[ni] = *(const bf16x8*)(Bsb + swz(wc * 32 + ni * 16 + (lane & 15), kb));
#pragma unroll
      for (int mi = 0; mi < 2; ++mi)
#pragma unroll
        for (int ni = 0; ni < 2; ++ni)
          acc[mi][ni] = __builtin_amdgcn_mfma_f32_16x16x32_bf16(af[mi], bfr[ni], acc[mi][ni], 0, 0, 0);
    }
    __syncthreads();
  }
#pragma unroll
  for (int ni = 0; ni < 2; ++ni) {
    const int n = bn * 64 + wc * 32 + ni * 16 + (lane & 15);
    const float bv = bp[n];
#pragma unroll
    for (int mi = 0; mi < 2; ++mi) {
#pragma unroll
      for (int rr = 0; rr < 4; ++rr) {
        const int gm = bm * 64 + wr * 32 + mi * 16 + ((lane >> 4) << 2) + rr;
        float v = acc[mi][ni][rr] + bv;
        if (ACT == 1) v = fmaxf(v, 0.f);
        const long o = (long)bz * ybs + (long)gm * N + n;
        if (WF32) Yf[o] = v;
        if (WBF) Ybf[o] = f2bf(v);
      }
    }
  }
}

// ---------------------------------------------------------------- attention
// One block per batch index s. QKV: (token=l*128+s, 1536) bf16; attention over l (L=8),
// H=8 heads, HD=64. Writes o (token,512) bf16.
__global__ __launch_bounds__(256) void attn_kernel(const unsigned short* __restrict__ qkv,
                                                   unsigned short* __restrict__ o) {
  __shared__ float P[512];  // [h][l][m]
  const int s = blockIdx.x;
  const int t = threadIdx.x;
#pragma unroll
  for (int rep = 0; rep < 2; ++rep) {
    const int idx = t + rep * 256;
    const int h = idx >> 6, l = (idx >> 3) & 7, m = idx & 7;
    const unsigned short* qp = qkv + (long)(l * 128 + s) * 1536 + h * 64;
    const unsigned short* kp = qkv + (long)(m * 128 + s) * 1536 + 512 + h * 64;
    float acc = 0.f;
#pragma unroll
    for (int c = 0; c < 64; c += 8) {
      u16x8 q8 = *(const u16x8*)(qp + c);
      u16x8 k8 = *(const u16x8*)(kp + c);
#pragma unroll
      for (int j = 0; j < 8; ++j) acc += bf2f(q8[j]) * bf2f(k8[j]);
    }
    P[idx] = acc * 0.125f;  // 1/sqrt(64)
  }
  __syncthreads();
  if (t < 64) {  // one (h,l) row each, softmax over m (8)
    const int base = t * 8;
    float mx = -1e30f;
#pragma unroll
    for (int m = 0; m < 8; ++m) mx = fmaxf(mx, P[base + m]);
    float e[8], sum = 0.f;
#pragma unroll
    for (int m = 0; m < 8; ++m) { e[m] = expf(P[base + m] - mx); sum += e[m]; }
    const float inv = 1.f / sum;
#pragma unroll
    for (int m = 0; m < 8; ++m) P[base + m] = e[m] * inv;
  }
  __syncthreads();
#pragma unroll
  for (int rep = 0; rep < 16; ++rep) {
    const int idx = t + rep * 256;  // l*512 + h*64 + d
    const int d = idx & 63, h = (idx >> 6) & 7, l = idx >> 9;
    float acc = 0.f;
#pragma unroll
    for (int m = 0; m < 8; ++m)
      acc += P[h * 64 + l * 8 + m] * bf2f(qkv[(long)(m * 128 + s) * 1536 + 1024 + h * 64 + d]);
    o[(long)(l * 128 + s) * 512 + h * 64 + d] = f2bf(acc);
  }
}

// ---------------------------------------------------------------- residual + LN
// h = LN(a [+ res]) * w + b ; writes fp32 (optional) and bf16. One block per row, D=512.
template <int RES, int WF32>
__global__ __launch_bounds__(256) void ln_kernel(const float* a, const float* res,
                                                 const float* __restrict__ w,
                                                 const float* __restrict__ bb, float* hf,
                                                 unsigned short* __restrict__ hbf) {
  __shared__ float red[8];
  const int row = blockIdx.x, t = threadIdx.x;
  const long base = (long)row * 512;
  float x0 = a[base + t], x1 = a[base + t + 256];
  if (RES) { x0 += res[base + t]; x1 += res[base + t + 256]; }
  float s = x0 + x1;
#pragma unroll
  for (int msk = 32; msk; msk >>= 1) s += __shfl_xor(s, msk, 64);
  if ((t & 63) == 0) red[t >> 6] = s;
  __syncthreads();
  const float mean = (red[0] + red[1] + red[2] + red[3]) * (1.f / 512.f);
  const float d0 = x0 - mean, d1 = x1 - mean;
  float v = d0 * d0 + d1 * d1;
#pragma unroll
  for (int msk = 32; msk; msk >>= 1) v += __shfl_xor(v, msk, 64);
  if ((t & 63) == 0) red[4 + (t >> 6)] = v;
  __syncthreads();
  const float var = (red[4] + red[5] + red[6] + red[7]) * (1.f / 512.f);
  const float inv = rsqrtf(var + 1e-5f);
  const float o0 = d0 * inv * w[t] + bb[t];
  const float o1 = d1 * inv * w[t + 256] + bb[t + 256];
  if (WF32) { hf[base + t] = o0; hf[base + t + 256] = o1; }
  hbf[base + t] = f2bf(o0);
  hbf[base + t + 256] = f2bf(o1);
}

// ---------------------------------------------------------------- phase C
// p[b,i,j,k] = sum_d sub[b,j,d]*obj[b,k,d]*(vsub[b,i,d]*vobj[b,i,d])
// block=(i,b): A[j,d]=sub*W staged fp32->bf16, B[k,d]=obj bf16; 128x128x512 MFMA GEMM.
__global__ __launch_bounds__(256) void phasec_kernel(const float* __restrict__ subp,
                                                     const unsigned short* __restrict__ objbf,
                                                     const float* __restrict__ vsub,
                                                     const float* __restrict__ vobj,
                                                     float* __restrict__ out) {
  __shared__ __align__(16) unsigned short As[128 * 64];
  __shared__ __align__(16) unsigned short Bs[128 * 64];
  __shared__ float Wl[512];
  const int t = threadIdx.x;
  const int i = blockIdx.x, b = blockIdx.y;
  const long base_bi = ((long)b * 128 + i) * 512;
  for (int d = t; d < 512; d += 256) Wl[d] = vsub[base_bi + d] * vobj[base_bi + d];
  __syncthreads();

  const int lane = t & 63, wv = t >> 6;
  const int wr = wv >> 1, wc = wv & 1;
  f32x4 acc[4][4] = {};
  char* Asb = (char*)As;
  char* Bsb = (char*)Bs;

  const int sr = t >> 1;  // 0..127 staging row
  const int sh = t & 1;   // 64B half of the row
  const long grow = ((long)b * 128 + sr) * 512;  // row sr: j-index (A) / k-index (B)

  for (int kt = 0; kt < 512; kt += 64) {
#pragma unroll
    for (int g = 0; g < 4; ++g) {
      const int c = sh * 32 + g * 8;  // element col in tile
      const float* gp = subp + grow + kt + c;
      f32x4 a = *(const f32x4*)gp;
      f32x4 b4 = *(const f32x4*)(gp + 4);
      const float* wp = Wl + kt + c;
      u16x8 oa;
      oa[0] = f2bf(a[0] * wp[0]); oa[1] = f2bf(a[1] * wp[1]);
      oa[2] = f2bf(a[2] * wp[2]); oa[3] = f2bf(a[3] * wp[3]);
      oa[4] = f2bf(b4[0] * wp[4]); oa[5] = f2bf(b4[1] * wp[5]);
      oa[6] = f2bf(b4[2] * wp[6]); oa[7] = f2bf(b4[3] * wp[7]);
      *(u16x8*)(Asb + swz(sr, sh * 64 + g * 16)) = oa;
      *(u16x8*)(Bsb + swz(sr, sh * 64 + g * 16)) = *(const u16x8*)(objbf + grow + kt + c);
    }
    __syncthreads();
#pragma unroll
    for (int kk = 0; kk < 2; ++kk) {
      const int kb = kk * 64 + ((lane >> 4) << 4);
      bf16x8 af[4], bfr[4];
#pragma unroll
      for (int mi = 0; mi < 4; ++mi)
        af[mi] = *(const bf16x8*)(Asb + swz(wr * 64 + mi * 16 + (lane & 15), kb));
#pragma unroll
      for (int ni = 0; ni < 4; ++ni)
        bfr[ni] = *(const bf16x8*)(Bsb + swz(wc * 64 + ni * 16 + (lane & 15), kb));
#pragma unroll
      for (int mi = 0; mi < 4; ++mi)
#pragma unroll
        for (int ni = 0; ni < 4; ++ni)
          acc[mi][ni] = __builtin_amdgcn_mfma_f32_16x16x32_bf16(af[mi], bfr[ni], acc[mi][ni], 0, 0, 0);
    }
    __syncthreads();
  }
  float* ob = out + ((long)b * 128 + i) * 128 * 128;
#pragma unroll
  for (int mi = 0; mi < 4; ++mi) {
#pragma unroll
    for (int rr = 0; rr < 4; ++rr) {
      const int j = wr * 64 + mi * 16 + ((lane >> 4) << 2) + rr;
      float* orow = ob + (long)j * 128 + wc * 64 + (lane & 15);
#pragma unroll
      for (int ni = 0; ni < 4; ++ni) orow[ni * 16] = acc[mi][ni][rr];
    }
  }
}

// ---------------------------------------------------------------- launch
extern "C" void kernel_launch(void* const* d_in, const int* in_sizes, int n_in, void* d_out,
                              int out_size, void* d_ws, size_t ws_size, hipStream_t stream) {
  const float* x          = (const float*)d_in[0];
  const float* attn_in_w  = (const float*)d_in[1];
  const float* attn_in_b  = (const float*)d_in[2];
  const float* attn_out_w = (const float*)d_in[3];
  const float* attn_out_b = (const float*)d_in[4];
  const float* ln1_w = (const float*)d_in[5];
  const float* ln1_b = (const float*)d_in[6];
  const float* ln2_w = (const float*)d_in[7];
  const float* ln2_b = (const float*)d_in[8];
  const float* ff1_w = (const float*)d_in[9];
  const float* ff1_b = (const float*)d_in[10];
  const float* ff2_w = (const float*)d_in[11];
  const float* ff2_b = (const float*)d_in[12];
  const float* fln_w = (const float*)d_in[13];
  const float* fln_b = (const float*)d_in[14];
  const float* mlp_w0 = (const float*)d_in[15];
  const float* mlp_b0 = (const float*)d_in[16];
  const float* mlp_w1 = (const float*)d_in[17];
  const float* mlp_b1 = (const float*)d_in[18];
  const float* mlp_w2 = (const float*)d_in[19];
  const float* mlp_b2 = (const float*)d_in[20];
  float* out = (float*)d_out;
  (void)in_sizes; (void)n_in; (void)out_size; (void)ws_size;

  char* ws = (char*)d_ws;
  size_t off = 0;
  auto alloc = [&](size_t bytes) -> void* {
    void* p = (void*)(ws + off);
    off += (bytes + 255) & ~(size_t)255;
    return p;
  };
  unsigned short* wq  = (unsigned short*)alloc((size_t)3 * 1536 * 512 * 2);
  unsigned short* wo  = (unsigned short*)alloc((size_t)3 * 512 * 512 * 2);
  unsigned short* wf1 = (unsigned short*)alloc((size_t)3 * 2048 * 512 * 2);
  unsigned short* wf2 = (unsigned short*)alloc((size_t)3 * 512 * 2048 * 2);
  unsigned short* wm0 = (unsigned short*)alloc((size_t)4 * 512 * 512 * 2);
  unsigned short* wm1 = (unsigned short*)alloc((size_t)4 * 512 * 512 * 2);
  unsigned short* wm2 = (unsigned short*)alloc((size_t)4 * 512 * 512 * 2);
  float* h            = (float*)alloc((size_t)1024 * 512 * 4);
  unsigned short* hbf = (unsigned short*)alloc((size_t)1024 * 512 * 2);
  unsigned short* t1  = (unsigned short*)alloc((size_t)1024 * 2048 * 2);
  float* t2           = (float*)alloc((size_t)1024 * 512 * 4);
  unsigned short* ao  = (unsigned short*)alloc((size_t)1024 * 512 * 2);
  unsigned short* z1  = (unsigned short*)alloc((size_t)4 * 1024 * 512 * 2);
  unsigned short* z2  = (unsigned short*)alloc((size_t)4 * 1024 * 512 * 2);
  float* hf4          = (float*)alloc((size_t)4 * 1024 * 512 * 4);
  unsigned short* hb4 = (unsigned short*)alloc((size_t)4 * 1024 * 512 * 2);

  auto cvt = [&](const float* s, unsigned short* d, float* df, int n) {
    int blocks = (n / 8 + 255) / 256;
    cvt_kernel<<<blocks, 256, 0, stream>>>(s, d, df, n);
  };
  cvt(attn_in_w, wq, nullptr, 3 * 1536 * 512);
  cvt(attn_out_w, wo, nullptr, 3 * 512 * 512);
  cvt(ff1_w, wf1, nullptr, 3 * 2048 * 512);
  cvt(ff2_w, wf2, nullptr, 3 * 512 * 2048);
  cvt(mlp_w0, wm0, nullptr, 4 * 512 * 512);
  cvt(mlp_w1, wm1, nullptr, 4 * 512 * 512);
  cvt(mlp_w2, wm2, nullptr, 4 * 512 * 512);
  cvt(x, hbf, h, 1024 * 512);

  for (int i = 0; i < 3; ++i) {
    gemm_kernel<0, 0, 1><<<dim3(24, 16, 1), 256, 0, stream>>>(
        hbf, wq + (long)i * 1536 * 512, attn_in_b + i * 1536, nullptr, t1, 1024, 1536, 512, 0, 0, 0, 0);
    attn_kernel<<<128, 256, 0, stream>>>(t1, ao);
    gemm_kernel<0, 1, 0><<<dim3(8, 16, 1), 256, 0, stream>>>(
        ao, wo + (long)i * 512 * 512, attn_out_b + i * 512, t2, nullptr, 1024, 512, 512, 0, 0, 0, 0);
    ln_kernel<1, 1><<<1024, 256, 0, stream>>>(t2, h, ln1_w + i * 512, ln1_b + i * 512, h, hbf);
    gemm_kernel<1, 0, 1><<<dim3(32, 16, 1), 256, 0, stream>>>(
        hbf, wf1 + (long)i * 2048 * 512, ff1_b + i * 2048, nullptr, t1, 1024, 2048, 512, 0, 0, 0, 0);
    gemm_kernel<0, 1, 0><<<dim3(8, 16, 1), 256, 0, stream>>>(
        t1, wf2 + (long)i * 512 * 2048, ff2_b + i * 512, t2, nullptr, 1024, 512, 2048, 0, 0, 0, 0);
    ln_kernel<1, 1><<<1024, 256, 0, stream>>>(t2, h, ln2_w + i * 512, ln2_b + i * 512, h, hbf);
  }
  ln_kernel<0, 0><<<1024, 256, 0, stream>>>(h, nullptr, fln_w, fln_b, h, hbf);

  // 4 head-MLPs batched over blockIdx.z
  gemm_kernel<1, 0, 1><<<dim3(8, 16, 4), 256, 0, stream>>>(
      hbf, wm0, mlp_b0, nullptr, z1, 1024, 512, 512, 0, 512 * 512, 512, 1024 * 512);
  gemm_kernel<1, 0, 1><<<dim3(8, 16, 4), 256, 0, stream>>>(
      z1, wm1, mlp_b1, nullptr, z2, 1024, 512, 512, 1024 * 512, 512 * 512, 512, 1024 * 512);
  gemm_kernel<0, 1, 1><<<dim3(8, 16, 4), 256, 0, stream>>>(
      z2, wm2, mlp_b2, hf4, hb4, 1024, 512, 512, 1024 * 512, 512 * 512, 512, 1024 * 512);

  // heads: 0=sub, 1=obj, 2=verb_sub, 3=verb_obj
  phasec_kernel<<<dim3(128, 8), 256, 0, stream>>>(
      hf4, hb4 + 1 * 1024 * 512, hf4 + 2L * 1024 * 512, hf4 + 3L * 1024 * 512, out);
}

// Round 2
// 379.616 us; speedup vs baseline: 1.1865x; 1.1865x over previous
//
#include <hip/hip_runtime.h>
#include <hip/hip_bf16.h>

#define DEV __device__ __forceinline__

typedef __attribute__((ext_vector_type(8))) short bf16x8;
typedef __attribute__((ext_vector_type(8))) unsigned short u16x8;
typedef __attribute__((ext_vector_type(4))) float f32x4;

DEV unsigned short f2bf(float f) {
  return __builtin_bit_cast(unsigned short, __float2bfloat16(f));
}
DEV float bf2f(unsigned short h) { return __uint_as_float(((unsigned int)h) << 16); }

// LDS swizzle: rows are 128 bytes; XOR 16B-slot with (row&7) -> bank-balanced
// ds_read_b128 / ds_write_b128 (G4 fix for stride-128B column reads).
DEV int swz(int row, int byteoff) { return row * 128 + (byteoff ^ ((row & 7) << 4)); }

// ---------------------------------------------------------------- cvt fp32->bf16 (x, with fp32 passthrough)
__global__ void cvt_kernel(const float* __restrict__ src, unsigned short* __restrict__ dst,
                           float* __restrict__ dstf, int n) {
  long i = ((long)blockIdx.x * blockDim.x + threadIdx.x) * 8;
  long stride = (long)gridDim.x * blockDim.x * 8;
  for (; i < n; i += stride) {
    f32x4 a = *(const f32x4*)(src + i);
    f32x4 b = *(const f32x4*)(src + i + 4);
    u16x8 o;
    o[0] = f2bf(a[0]); o[1] = f2bf(a[1]); o[2] = f2bf(a[2]); o[3] = f2bf(a[3]);
    o[4] = f2bf(b[0]); o[5] = f2bf(b[1]); o[6] = f2bf(b[2]); o[7] = f2bf(b[3]);
    *(u16x8*)(dst + i) = o;
    if (dstf) { *(f32x4*)(dstf + i) = a; *(f32x4*)(dstf + i + 4) = b; }
  }
}

// all 7 weight tensors in one launch
struct CvtJobs { const float* s[7]; unsigned short* d[7]; int n[7]; };
__global__ void cvtw_kernel(CvtJobs J) {
  const int seg = blockIdx.y;
  const float* __restrict__ src = J.s[seg];
  unsigned short* __restrict__ dst = J.d[seg];
  const int n = J.n[seg];
  long i = ((long)blockIdx.x * blockDim.x + threadIdx.x) * 8;
  long stride = (long)gridDim.x * blockDim.x * 8;
  for (; i < n; i += stride) {
    f32x4 a = *(const f32x4*)(src + i);
    f32x4 b = *(const f32x4*)(src + i + 4);
    u16x8 o;
    o[0] = f2bf(a[0]); o[1] = f2bf(a[1]); o[2] = f2bf(a[2]); o[3] = f2bf(a[3]);
    o[4] = f2bf(b[0]); o[5] = f2bf(b[1]); o[6] = f2bf(b[2]); o[7] = f2bf(b[3]);
    *(u16x8*)(dst + i) = o;
  }
}

// ---------------------------------------------------------------- GEMM
// Y[m,n] = act( sum_k X[m,k]*W[n,k] + bias[n] ), X:(M,K) bf16, W:(N,K) bf16.
// BM x 64 tile, BK=64, 4 waves (2x2). Reg-staged double-buffered pipeline:
// iter ki: ds_write regs(k=ki+1)->buf^1 ; issue loads k=ki+2 -> regs ;
//          MFMA from buf ; __syncthreads (loads had a full compute phase to land).
template <int BM, int ACT, int WF32, int WBF>
__global__ __launch_bounds__(256) void gemm_kernel(
    const unsigned short* __restrict__ X, const unsigned short* __restrict__ Wt,
    const float* __restrict__ bias, float* Yf, unsigned short* __restrict__ Ybf,
    int M, int N, int K, long xbs, long wbs, long bbs, long ybs) {
  constexpr int CA = (BM * 64) / (256 * 8);  // A 16B-chunks per thread (1 or 2)
  constexpr int ABY = BM * 64 * 2;
  constexpr int BBY = 64 * 64 * 2;
  constexpr int MI = BM / 32;
  __shared__ __align__(16) char Asb[2 * ABY];
  __shared__ __align__(16) char Bsb[2 * BBY];
  const int t = threadIdx.x;
  const int bn = blockIdx.x, bm = blockIdx.y, bz = blockIdx.z;
  const unsigned short* Xp = X + (long)bz * xbs;
  const unsigned short* Wp = Wt + (long)bz * wbs;

  const int lane = t & 63, wv = t >> 6;
  const int wr = wv >> 1, wc = wv & 1;
  f32x4 acc[MI][2] = {};

  int rowA[CA], slotA[CA], rowB[2], slotB[2];
#pragma unroll
  for (int c = 0; c < CA; ++c) { int id = c * 256 + t; rowA[c] = id >> 3; slotA[c] = id & 7; }
#pragma unroll
  for (int c = 0; c < 2; ++c) { int id = c * 256 + t; rowB[c] = id >> 3; slotB[c] = id & 7; }

  u16x8 ra[CA], rb[2];
  auto load = [&](int kt) {
#pragma unroll
    for (int c = 0; c < CA; ++c)
      ra[c] = *(const u16x8*)(Xp + (long)(bm * BM + rowA[c]) * K + kt + slotA[c] * 8);
#pragma unroll
    for (int c = 0; c < 2; ++c)
      rb[c] = *(const u16x8*)(Wp + (long)(bn * 64 + rowB[c]) * K + kt + slotB[c] * 8);
  };
  auto store = [&](int cur) {
#pragma unroll
    for (int c = 0; c < CA; ++c)
      *(u16x8*)(Asb + cur * ABY + swz(rowA[c], slotA[c] * 16)) = ra[c];
#pragma unroll
    for (int c = 0; c < 2; ++c)
      *(u16x8*)(Bsb + cur * BBY + swz(rowB[c], slotB[c] * 16)) = rb[c];
  };

  const int NT = K >> 6;
  load(0);
  store(0);
  load(64);
  __syncthreads();
  for (int ki = 0; ki < NT; ++ki) {
    const int cur = ki & 1;
    if (ki + 1 < NT) store(cur ^ 1);
    if (ki + 2 < NT) load((ki + 2) << 6);
#pragma unroll
    for (int kk = 0; kk < 2; ++kk) {
      const int kb = kk * 64 + ((lane >> 4) << 4);
      bf16x8 af[MI], bfv[2];
#pragma unroll
      for (int mi = 0; mi < MI; ++mi)
        af[mi] = *(const bf16x8*)(Asb + cur * ABY + swz(wr * (MI * 16) + mi * 16 + (lane & 15), kb));
#pragma unroll
      for (int ni = 0; ni < 2; ++ni)
        bfv[ni] = *(const bf16x8*)(Bsb + cur * BBY + swz(wc * 32 + ni * 16 + (lane & 15), kb));
#pragma unroll
      for (int mi = 0; mi < MI; ++mi)
#pragma unroll
        for (int ni = 0; ni < 2; ++ni)
          acc[mi][ni] = __builtin_amdgcn_mfma_f32_16x16x32_bf16(af[mi], bfv[ni], acc[mi][ni], 0, 0, 0);
    }
    __syncthreads();
  }
#pragma unroll
  for (int ni = 0; ni < 2; ++ni) {
    const int n = bn * 64 + wc * 32 + ni * 16 + (lane & 15);
    const float bv = bias[(long)bz * bbs + n];
#pragma unroll
    for (int mi = 0; mi < MI; ++mi) {
#pragma unroll
      for (int rr = 0; rr < 4; ++rr) {
        const int gm = bm * BM + wr * (MI * 16) + mi * 16 + ((lane >> 4) << 2) + rr;
        float v = acc[mi][ni][rr] + bv;
        if (ACT == 1) v = fmaxf(v, 0.f);
        const long o = (long)bz * ybs + (long)gm * N + n;
        if (WF32) Yf[o] = v;
        if (WBF) Ybf[o] = f2bf(v);
      }
    }
  }
}

// ---------------------------------------------------------------- attention
__global__ __launch_bounds__(256) void attn_kernel(const unsigned short* __restrict__ qkv,
                                                   unsigned short* __restrict__ o) {
  __shared__ float P[512];  // [h][l][m]
  const int s = blockIdx.x;
  const int t = threadIdx.x;
#pragma unroll
  for (int rep = 0; rep < 2; ++rep) {
    const int idx = t + rep * 256;
    const int h = idx >> 6, l = (idx >> 3) & 7, m = idx & 7;
    const unsigned short* qp = qkv + (long)(l * 128 + s) * 1536 + h * 64;
    const unsigned short* kp = qkv + (long)(m * 128 + s) * 1536 + 512 + h * 64;
    float acc = 0.f;
#pragma unroll
    for (int c = 0; c < 64; c += 8) {
      u16x8 q8 = *(const u16x8*)(qp + c);
      u16x8 k8 = *(const u16x8*)(kp + c);
#pragma unroll
      for (int j = 0; j < 8; ++j) acc += bf2f(q8[j]) * bf2f(k8[j]);
    }
    P[idx] = acc * 0.125f;
  }
  __syncthreads();
  if (t < 64) {
    const int base = t * 8;
    float mx = -1e30f;
#pragma unroll
    for (int m = 0; m < 8; ++m) mx = fmaxf(mx, P[base + m]);
    float e[8], sum = 0.f;
#pragma unroll
    for (int m = 0; m < 8; ++m) { e[m] = expf(P[base + m] - mx); sum += e[m]; }
    const float inv = 1.f / sum;
#pragma unroll
    for (int m = 0; m < 8; ++m) P[base + m] = e[m] * inv;
  }
  __syncthreads();
#pragma unroll
  for (int rep = 0; rep < 16; ++rep) {
    const int idx = t + rep * 256;  // l*512 + h*64 + d
    const int d = idx & 63, h = (idx >> 6) & 7, l = idx >> 9;
    float acc = 0.f;
#pragma unroll
    for (int m = 0; m < 8; ++m)
      acc += P[h * 64 + l * 8 + m] * bf2f(qkv[(long)(m * 128 + s) * 1536 + 1024 + h * 64 + d]);
    o[(long)(l * 128 + s) * 512 + h * 64 + d] = f2bf(acc);
  }
}

// ---------------------------------------------------------------- residual + LN
template <int RES, int WF32>
__global__ __launch_bounds__(256) void ln_kernel(const float* a, const float* res,
                                                 const float* __restrict__ w,
                                                 const float* __restrict__ bb, float* hf,
                                                 unsigned short* __restrict__ hbf) {
  __shared__ float red[8];
  const int row = blockIdx.x, t = threadIdx.x;
  const long base = (long)row * 512;
  float x0 = a[base + t], x1 = a[base + t + 256];
  if (RES) { x0 += res[base + t]; x1 += res[base + t + 256]; }
  float s = x0 + x1;
#pragma unroll
  for (int msk = 32; msk; msk >>= 1) s += __shfl_xor(s, msk, 64);
  if ((t & 63) == 0) red[t >> 6] = s;
  __syncthreads();
  const float mean = (red[0] + red[1] + red[2] + red[3]) * (1.f / 512.f);
  const float d0 = x0 - mean, d1 = x1 - mean;
  float v = d0 * d0 + d1 * d1;
#pragma unroll
  for (int msk = 32; msk; msk >>= 1) v += __shfl_xor(v, msk, 64);
  if ((t & 63) == 0) red[4 + (t >> 6)] = v;
  __syncthreads();
  const float var = (red[4] + red[5] + red[6] + red[7]) * (1.f / 512.f);
  const float inv = rsqrtf(var + 1e-5f);
  const float o0 = d0 * inv * w[t] + bb[t];
  const float o1 = d1 * inv * w[t + 256] + bb[t + 256];
  if (WF32) { hf[base + t] = o0; hf[base + t + 256] = o1; }
  hbf[base + t] = f2bf(o0);
  hbf[base + t + 256] = f2bf(o1);
}

// ---------------------------------------------------------------- phase C
// p[b,i,j,k] = sum_d sub[b,j,d]*obj[b,k,d]*(vsub[b,i,d]*vobj[b,i,d])
// block=(i,b): A[j,d]=sub*W (fp32 staged ->bf16 at ds_write time), B[k,d]=obj bf16.
// Same 1-barrier double-buffered pipeline as gemm_kernel.
__global__ __launch_bounds__(256) void phasec_kernel(const float* __restrict__ subp,
                                                     const unsigned short* __restrict__ objbf,
                                                     const float* __restrict__ vsub,
                                                     const float* __restrict__ vobj,
                                                     float* __restrict__ out) {
  constexpr int ABY = 128 * 64 * 2;  // 16 KiB per buffer per operand
  __shared__ __align__(16) char Asb[2 * ABY];
  __shared__ __align__(16) char Bsb[2 * ABY];
  __shared__ float Wl[512];
  const int t = threadIdx.x;
  const int i = blockIdx.x, b = blockIdx.y;
  const long base_bi = ((long)b * 128 + i) * 512;
  for (int d = t; d < 512; d += 256) Wl[d] = vsub[base_bi + d] * vobj[base_bi + d];

  const int lane = t & 63, wv = t >> 6;
  const int wr = wv >> 1, wc = wv & 1;
  f32x4 acc[4][4] = {};

  int row[4], slot[4];
#pragma unroll
  for (int c = 0; c < 4; ++c) { int id = c * 256 + t; row[c] = id >> 3; slot[c] = id & 7; }

  f32x4 fa[4][2];
  u16x8 rb[4];
  auto load = [&](int kt) {
#pragma unroll
    for (int c = 0; c < 4; ++c) {
      const long g = ((long)b * 128 + row[c]) * 512 + kt + slot[c] * 8;
      fa[c][0] = *(const f32x4*)(subp + g);
      fa[c][1] = *(const f32x4*)(subp + g + 4);
      rb[c] = *(const u16x8*)(objbf + g);
    }
  };
  auto store = [&](int cur, int ktd) {
#pragma unroll
    for (int c = 0; c < 4; ++c) {
      const float* wp = Wl + ktd + slot[c] * 8;
      f32x4 w0 = *(const f32x4*)wp;
      f32x4 w1 = *(const f32x4*)(wp + 4);
      u16x8 oa;
      oa[0] = f2bf(fa[c][0][0] * w0[0]); oa[1] = f2bf(fa[c][0][1] * w0[1]);
      oa[2] = f2bf(fa[c][0][2] * w0[2]); oa[3] = f2bf(fa[c][0][3] * w0[3]);
      oa[4] = f2bf(fa[c][1][0] * w1[0]); oa[5] = f2bf(fa[c][1][1] * w1[1]);
      oa[6] = f2bf(fa[c][1][2] * w1[2]); oa[7] = f2bf(fa[c][1][3] * w1[3]);
      *(u16x8*)(Asb + cur * ABY + swz(row[c], slot[c] * 16)) = oa;
      *(u16x8*)(Bsb + cur * ABY + swz(row[c], slot[c] * 16)) = rb[c];
    }
  };

  __syncthreads();  // Wl visible before store() reads it
  load(0);
  store(0, 0);
  load(64);
  __syncthreads();
  for (int ki = 0; ki < 8; ++ki) {
    const int cur = ki & 1;
    if (ki + 1 < 8) store(cur ^ 1, (ki + 1) * 64);
    if (ki + 2 < 8) load((ki + 2) * 64);
#pragma unroll
    for (int kk = 0; kk < 2; ++kk) {
      const int kb = kk * 64 + ((lane >> 4) << 4);
      bf16x8 af[4], bfv[4];
#pragma unroll
      for (int mi = 0; mi < 4; ++mi)
        af[mi] = *(const bf16x8*)(Asb + cur * ABY + swz(wr * 64 + mi * 16 + (lane & 15), kb));
#pragma unroll
      for (int ni = 0; ni < 4; ++ni)
        bfv[ni] = *(const bf16x8*)(Bsb + cur * ABY + swz(wc * 64 + ni * 16 + (lane & 15), kb));
#pragma unroll
      for (int mi = 0; mi < 4; ++mi)
#pragma unroll
        for (int ni = 0; ni < 4; ++ni)
          acc[mi][ni] = __builtin_amdgcn_mfma_f32_16x16x32_bf16(af[mi], bfv[ni], acc[mi][ni], 0, 0, 0);
    }
    __syncthreads();
  }
  float* ob = out + ((long)b * 128 + i) * 128 * 128;
#pragma unroll
  for (int mi = 0; mi < 4; ++mi) {
#pragma unroll
    for (int rr = 0; rr < 4; ++rr) {
      const int j = wr * 64 + mi * 16 + ((lane >> 4) << 2) + rr;
      float* orow = ob + (long)j * 128 + wc * 64 + (lane & 15);
#pragma unroll
      for (int ni = 0; ni < 4; ++ni) orow[ni * 16] = acc[mi][ni][rr];
    }
  }
}

// ---------------------------------------------------------------- launch
extern "C" void kernel_launch(void* const* d_in, const int* in_sizes, int n_in, void* d_out,
                              int out_size, void* d_ws, size_t ws_size, hipStream_t stream) {
  const float* x          = (const float*)d_in[0];
  const float* attn_in_w  = (const float*)d_in[1];
  const float* attn_in_b  = (const float*)d_in[2];
  const float* attn_out_w = (const float*)d_in[3];
  const float* attn_out_b = (const float*)d_in[4];
  const float* ln1_w = (const float*)d_in[5];
  const float* ln1_b = (const float*)d_in[6];
  const float* ln2_w = (const float*)d_in[7];
  const float* ln2_b = (const float*)d_in[8];
  const float* ff1_w = (const float*)d_in[9];
  const float* ff1_b = (const float*)d_in[10];
  const float* ff2_w = (const float*)d_in[11];
  const float* ff2_b = (const float*)d_in[12];
  const float* fln_w = (const float*)d_in[13];
  const float* fln_b = (const float*)d_in[14];
  const float* mlp_w0 = (const float*)d_in[15];
  const float* mlp_b0 = (const float*)d_in[16];
  const float* mlp_w1 = (const float*)d_in[17];
  const float* mlp_b1 = (const float*)d_in[18];
  const float* mlp_w2 = (const float*)d_in[19];
  const float* mlp_b2 = (const float*)d_in[20];
  float* out = (float*)d_out;
  (void)in_sizes; (void)n_in; (void)out_size; (void)ws_size;

  char* ws = (char*)d_ws;
  size_t off = 0;
  auto alloc = [&](size_t bytes) -> void* {
    void* p = (void*)(ws + off);
    off += (bytes + 255) & ~(size_t)255;
    return p;
  };
  unsigned short* wq  = (unsigned short*)alloc((size_t)3 * 1536 * 512 * 2);
  unsigned short* wo  = (unsigned short*)alloc((size_t)3 * 512 * 512 * 2);
  unsigned short* wf1 = (unsigned short*)alloc((size_t)3 * 2048 * 512 * 2);
  unsigned short* wf2 = (unsigned short*)alloc((size_t)3 * 512 * 2048 * 2);
  unsigned short* wm0 = (unsigned short*)alloc((size_t)4 * 512 * 512 * 2);
  unsigned short* wm1 = (unsigned short*)alloc((size_t)4 * 512 * 512 * 2);
  unsigned short* wm2 = (unsigned short*)alloc((size_t)4 * 512 * 512 * 2);
  float* h            = (float*)alloc((size_t)1024 * 512 * 4);
  unsigned short* hbf = (unsigned short*)alloc((size_t)1024 * 512 * 2);
  unsigned short* t1  = (unsigned short*)alloc((size_t)1024 * 2048 * 2);
  float* t2           = (float*)alloc((size_t)1024 * 512 * 4);
  unsigned short* ao  = (unsigned short*)alloc((size_t)1024 * 512 * 2);
  unsigned short* z1  = (unsigned short*)alloc((size_t)4 * 1024 * 512 * 2);
  unsigned short* z2  = (unsigned short*)alloc((size_t)4 * 1024 * 512 * 2);
  float* hf4          = (float*)alloc((size_t)4 * 1024 * 512 * 4);
  unsigned short* hb4 = (unsigned short*)alloc((size_t)4 * 1024 * 512 * 2);

  CvtJobs J;
  J.s[0] = attn_in_w;  J.d[0] = wq;  J.n[0] = 3 * 1536 * 512;
  J.s[1] = attn_out_w; J.d[1] = wo;  J.n[1] = 3 * 512 * 512;
  J.s[2] = ff1_w;      J.d[2] = wf1; J.n[2] = 3 * 2048 * 512;
  J.s[3] = ff2_w;      J.d[3] = wf2; J.n[3] = 3 * 512 * 2048;
  J.s[4] = mlp_w0;     J.d[4] = wm0; J.n[4] = 4 * 512 * 512;
  J.s[5] = mlp_w1;     J.d[5] = wm1; J.n[5] = 4 * 512 * 512;
  J.s[6] = mlp_w2;     J.d[6] = wm2; J.n[6] = 4 * 512 * 512;
  cvtw_kernel<<<dim3(512, 7), 256, 0, stream>>>(J);
  cvt_kernel<<<256, 256, 0, stream>>>(x, hbf, h, 1024 * 512);

  for (int i = 0; i < 3; ++i) {
    gemm_kernel<64, 0, 0, 1><<<dim3(24, 16, 1), 256, 0, stream>>>(
        hbf, wq + (long)i * 1536 * 512, attn_in_b + i * 1536, nullptr, t1, 1024, 1536, 512, 0, 0, 0, 0);
    attn_kernel<<<128, 256, 0, stream>>>(t1, ao);
    gemm_kernel<32, 0, 1, 0><<<dim3(8, 32, 1), 256, 0, stream>>>(
        ao, wo + (long)i * 512 * 512, attn_out_b + i * 512, t2, nullptr, 1024, 512, 512, 0, 0, 0, 0);
    ln_kernel<1, 1><<<1024, 256, 0, stream>>>(t2, h, ln1_w + i * 512, ln1_b + i * 512, h, hbf);
    gemm_kernel<64, 1, 0, 1><<<dim3(32, 16, 1), 256, 0, stream>>>(
        hbf, wf1 + (long)i * 2048 * 512, ff1_b + i * 2048, nullptr, t1, 1024, 2048, 512, 0, 0, 0, 0);
    gemm_kernel<32, 0, 1, 0><<<dim3(8, 32, 1), 256, 0, stream>>>(
        t1, wf2 + (long)i * 512 * 2048, ff2_b + i * 512, t2, nullptr, 1024, 512, 2048, 0, 0, 0, 0);
    ln_kernel<1, 1><<<1024, 256, 0, stream>>>(t2, h, ln2_w + i * 512, ln2_b + i * 512, h, hbf);
  }
  ln_kernel<0, 0><<<1024, 256, 0, stream>>>(h, nullptr, fln_w, fln_b, h, hbf);

  // 4 head-MLPs batched over blockIdx.z
  gemm_kernel<32, 1, 0, 1><<<dim3(8, 32, 4), 256, 0, stream>>>(
      hbf, wm0, mlp_b0, nullptr, z1, 1024, 512, 512, 0, 512 * 512, 512, 1024 * 512);
  gemm_kernel<32, 1, 0, 1><<<dim3(8, 32, 4), 256, 0, stream>>>(
      z1, wm1, mlp_b1, nullptr, z2, 1024, 512, 512, 1024 * 512, 512 * 512, 512, 1024 * 512);
  gemm_kernel<32, 0, 1, 1><<<dim3(8, 32, 4), 256, 0, stream>>>(
      z2, wm2, mlp_b2, hf4, hb4, 1024, 512, 512, 1024 * 512, 512 * 512, 512, 1024 * 512);

  // heads: 0=sub, 1=obj, 2=verb_sub, 3=verb_obj
  phasec_kernel<<<dim3(128, 8), 256, 0, stream>>>(
      hf4, hb4 + 1 * 1024 * 512, hf4 + 2L * 1024 * 512, hf4 + 3L * 1024 * 512, out);
}